// Round 2
// baseline (257.958 us; speedup 1.0000x reference)
//
#include <hip/hip_runtime.h>
#include <math.h>

namespace {
constexpr int kB   = 8192;
constexpr int kT   = 16;
constexpr int kXU  = 36;
constexpr int kCTX = 16;
constexpr int kK   = 4;
constexpr int kH   = 32;
constexpr int kBT  = kB * kT;            // 131072 samples
constexpr int kIN  = kXU + kCTX;         // 52
constexpr int kNB  = kBT / 256;          // 512 blocks, main kernel
constexpr int kNC  = (kB * kCTX) / 256;  // 512 blocks, ctx/kl kernel
}

// ---------------------------------------------------------------------------
// context = mu + sigma*noise  (written to d_out+1), plus per-block KL partials
// ---------------------------------------------------------------------------
__global__ __launch_bounds__(256) void ctx_kl_kernel(
    const float* __restrict__ mu, const float* __restrict__ sg,
    const float* __restrict__ nz, float* __restrict__ ctx_out,
    float* __restrict__ kl_part)
{
  const int tid = threadIdx.x;
  const int i = blockIdx.x * 256 + tid;
  float m = mu[i], s = sg[i], n = nz[i];
  ctx_out[i] = fmaf(s, n, m);
  // kl = log(1/s) + (s^2 + m^2)/2 - 1/2
  float kl = 0.5f * (s * s + m * m) - logf(s) - 0.5f;

  __shared__ float red[256];
  red[tid] = kl;
  __syncthreads();
  for (int off = 128; off > 0; off >>= 1) {
    if (tid < off) red[tid] += red[tid + off];
    __syncthreads();
  }
  if (tid == 0) kl_part[blockIdx.x] = red[0];
}

// ---------------------------------------------------------------------------
// main: per-sample MLP fwd + analytic Jacobian + squared-error partial sums
// ---------------------------------------------------------------------------
__global__ __launch_bounds__(256) void main_kernel(
    const float* __restrict__ traj,
    const float* __restrict__ tgtc,
    const float* __restrict__ tgtg,
    const float* __restrict__ mu,
    const float* __restrict__ sg,
    const float* __restrict__ nz,
    const float* __restrict__ W1,
    const float* __restrict__ b1,
    const float* __restrict__ W2,
    const float* __restrict__ b2,
    const float* __restrict__ W3,
    const float* __restrict__ b3,
    float* __restrict__ part_c,
    float* __restrict__ part_g)
{
  const int tid = threadIdx.x;
  const int s   = blockIdx.x * 256 + tid;
  const int b   = s >> 4;  // t = s & 15

  // ---- input vector x[52] = [traj(36) | mu + sigma*noise (16)] ----
  float x[kIN];
  {
    const float4* t4 = reinterpret_cast<const float4*>(traj + (size_t)s * kXU);
#pragma unroll
    for (int i = 0; i < kXU / 4; ++i) {
      float4 v = t4[i];
      x[4 * i + 0] = v.x; x[4 * i + 1] = v.y;
      x[4 * i + 2] = v.z; x[4 * i + 3] = v.w;
    }
    const float4* m4 = reinterpret_cast<const float4*>(mu + (size_t)b * kCTX);
    const float4* s4 = reinterpret_cast<const float4*>(sg + (size_t)b * kCTX);
    const float4* n4 = reinterpret_cast<const float4*>(nz + (size_t)b * kCTX);
#pragma unroll
    for (int c = 0; c < kCTX / 4; ++c) {
      float4 mv = m4[c], sv = s4[c], nv = n4[c];
      x[kXU + 4 * c + 0] = fmaf(sv.x, nv.x, mv.x);
      x[kXU + 4 * c + 1] = fmaf(sv.y, nv.y, mv.y);
      x[kXU + 4 * c + 2] = fmaf(sv.z, nv.z, mv.z);
      x[kXU + 4 * c + 3] = fmaf(sv.w, nv.w, mv.w);
    }
  }

  // ---- layer 1: h1 = relu(x @ W1 + b1) ----  (weights uniform -> s_load)
  float h1[kH];
#pragma unroll
  for (int j = 0; j < kH; ++j) h1[j] = b1[j];
#pragma unroll
  for (int i = 0; i < kIN; ++i) {
#pragma unroll
    for (int j = 0; j < kH; ++j) h1[j] = fmaf(x[i], W1[i * kH + j], h1[j]);
  }
#pragma unroll
  for (int j = 0; j < kH; ++j) h1[j] = fmaxf(h1[j], 0.0f);

  // ---- layer 2: h2 = relu(h1 @ W2 + b2) ----
  float h2[kH];
#pragma unroll
  for (int j = 0; j < kH; ++j) h2[j] = b2[j];
#pragma unroll
  for (int i = 0; i < kH; ++i) {
#pragma unroll
    for (int j = 0; j < kH; ++j) h2[j] = fmaf(h1[i], W2[i * kH + j], h2[j]);
  }
#pragma unroll
  for (int j = 0; j < kH; ++j) h2[j] = fmaxf(h2[j], 0.0f);

  // ---- constraint head + squared error ----
  float errc = 0.0f;
  {
    float4 tc = *reinterpret_cast<const float4*>(tgtc + (size_t)s * kK);
    float tcv[4] = {tc.x, tc.y, tc.z, tc.w};
#pragma unroll
    for (int k = 0; k < kK; ++k) {
      float p = b3[k];
#pragma unroll
      for (int h = 0; h < kH; ++h) p = fmaf(h2[h], W3[h * kK + k], p);
      float d = p - tcv[k];
      errc = fmaf(d, d, errc);
    }
  }

  // ---- analytic Jacobian J[k][x] = sum_j m1[j]*S[j][k]*W1[x][j],
  //      S[j][k] = sum_h m2[h]*W3[h][k]*W2[j][h] ----
  float errg = 0.0f;
  const float* gbase = tgtg + (size_t)s * (kK * kXU);
#pragma unroll
  for (int k = 0; k < kK; ++k) {
    float a[kH];
#pragma unroll
    for (int h = 0; h < kH; ++h) a[h] = (h2[h] > 0.0f) ? W3[h * kK + k] : 0.0f;
    float t[kH];
#pragma unroll
    for (int j = 0; j < kH; ++j) {
      float acc = 0.0f;
#pragma unroll
      for (int h = 0; h < kH; ++h) acc = fmaf(a[h], W2[j * kH + h], acc);
      t[j] = (h1[j] > 0.0f) ? acc : 0.0f;
    }
#pragma unroll
    for (int xq = 0; xq < kXU / 4; ++xq) {
      float4 g = *reinterpret_cast<const float4*>(gbase + k * kXU + xq * 4);
      float gv[4] = {g.x, g.y, g.z, g.w};
#pragma unroll
      for (int xi = 0; xi < 4; ++xi) {
        const int xx = xq * 4 + xi;
        float J = 0.0f;
#pragma unroll
        for (int j = 0; j < kH; ++j) J = fmaf(t[j], W1[xx * kH + j], J);
        float d = J - gv[xi];
        errg = fmaf(d, d, errg);
      }
    }
  }

  // ---- block reduction (deterministic) ----
  __shared__ float red[256];
  red[tid] = errc;
  __syncthreads();
  for (int off = 128; off > 0; off >>= 1) {
    if (tid < off) red[tid] += red[tid + off];
    __syncthreads();
  }
  if (tid == 0) part_c[blockIdx.x] = red[0];
  __syncthreads();
  red[tid] = errg;
  __syncthreads();
  for (int off = 128; off > 0; off >>= 1) {
    if (tid < off) red[tid] += red[tid + off];
    __syncthreads();
  }
  if (tid == 0) part_g[blockIdx.x] = red[0];
}

// ---------------------------------------------------------------------------
// finalize: sum the 3 partial arrays (512 each), write loss to out[0]
// ---------------------------------------------------------------------------
__global__ __launch_bounds__(256) void finalize_kernel(
    const float* __restrict__ ws, float* __restrict__ out)
{
  const int tid = threadIdx.x;
  float kl = ws[tid] + ws[tid + 256];
  float c  = ws[512 + tid] + ws[512 + tid + 256];
  float g  = ws[1024 + tid] + ws[1024 + tid + 256];
  __shared__ float rk[256], rc[256], rg[256];
  rk[tid] = kl; rc[tid] = c; rg[tid] = g;
  __syncthreads();
  for (int off = 128; off > 0; off >>= 1) {
    if (tid < off) {
      rk[tid] += rk[tid + off];
      rc[tid] += rc[tid + off];
      rg[tid] += rg[tid + off];
    }
    __syncthreads();
  }
  if (tid == 0) {
    float loss = rc[0] / (float)(kBT * kK)
               + rg[0] / ((float)kBT * (float)(kK * kXU))
               + rk[0] / (float)(kB * kCTX);
    out[0] = loss;
  }
}

// ---------------------------------------------------------------------------
extern "C" void kernel_launch(void* const* d_in, const int* in_sizes, int n_in,
                              void* d_out, int out_size, void* d_ws, size_t ws_size,
                              hipStream_t stream)
{
  const float* traj = (const float*)d_in[0];
  const float* tgtc = (const float*)d_in[1];
  const float* tgtg = (const float*)d_in[2];
  const float* mu   = (const float*)d_in[3];
  const float* sg   = (const float*)d_in[4];
  const float* nz   = (const float*)d_in[5];
  const float* W1   = (const float*)d_in[6];
  const float* b1   = (const float*)d_in[7];
  const float* W2   = (const float*)d_in[8];
  const float* b2   = (const float*)d_in[9];
  const float* W3   = (const float*)d_in[10];
  const float* b3   = (const float*)d_in[11];

  float* out = (float*)d_out;
  float* ws  = (float*)d_ws;
  float* kl_part = ws;          // [0, 512)
  float* pc      = ws + 512;    // [512, 1024)
  float* pg      = ws + 1024;   // [1024, 1536)

  // context (d_out[1:]) + KL partials
  ctx_kl_kernel<<<kNC, 256, 0, stream>>>(mu, sg, nz, out + 1, kl_part);
  // per-sample MLP + Jacobian + error partials
  main_kernel<<<kNB, 256, 0, stream>>>(traj, tgtc, tgtg, mu, sg, nz,
                                       W1, b1, W2, b2, W3, b3, pc, pg);
  // loss scalar
  finalize_kernel<<<1, 256, 0, stream>>>(ws, out);
}

// Round 3
// 42.201 us; speedup vs baseline: 6.1127x; 6.1127x over previous
//
#include <hip/hip_runtime.h>
#include <math.h>

typedef __attribute__((ext_vector_type(8))) short bf16x8;
typedef __attribute__((ext_vector_type(4))) float f32x4;

namespace {
constexpr int kB   = 8192;
constexpr int kT   = 16;
constexpr int kXU  = 36;
constexpr int kCTX = 16;
constexpr int kK   = 4;
constexpr int kH   = 32;
constexpr int kBT  = kB * kT;             // 131072 samples
constexpr int kTiles = kBT / 16;          // 8192 tiles (1 tile = 16 samples = one b)
constexpr int kMainBlocks = 1024;         // 4 waves/block -> 4096 waves, 2 tiles/wave
constexpr int kNC = (kB * kCTX) / 256;    // 512 blocks for ctx/kl
}

__device__ __forceinline__ unsigned short f2bf(float f) {
  union { float f; unsigned u; } v; v.f = f;
  unsigned u = v.u + 0x7FFFu + ((v.u >> 16) & 1u);   // RNE
  return (unsigned short)(u >> 16);
}

__device__ __forceinline__ f32x4 mfma16(bf16x8 a, bf16x8 b, f32x4 c) {
  return __builtin_amdgcn_mfma_f32_16x16x32_bf16(a, b, c, 0, 0, 0);
}

// ---------------------------------------------------------------------------
// context = mu + sigma*noise  (written to d_out+1), plus per-block KL partials
// ---------------------------------------------------------------------------
__global__ __launch_bounds__(256) void ctx_kl_kernel(
    const float* __restrict__ mu, const float* __restrict__ sg,
    const float* __restrict__ nz, float* __restrict__ ctx_out,
    float* __restrict__ kl_part)
{
  const int tid = threadIdx.x;
  const int i = blockIdx.x * 256 + tid;
  float m = mu[i], s = sg[i], n = nz[i];
  ctx_out[i] = fmaf(s, n, m);
  float kl = 0.5f * (s * s + m * m) - logf(s) - 0.5f;

  __shared__ float red[256];
  red[tid] = kl;
  __syncthreads();
  for (int off = 128; off > 0; off >>= 1) {
    if (tid < off) red[tid] += red[tid + off];
    __syncthreads();
  }
  if (tid == 0) kl_part[blockIdx.x] = red[0];
}

// ---------------------------------------------------------------------------
// main: per-wave MFMA pipeline. Wave = 16 samples (one b). Weights live in
// registers as persistent B-fragments. LDS scratch (per-wave private) is used
// only for D-layout -> A-layout transposes; same-wave DS ops are in-order so
// no barriers are needed.
//
// MFMA layouts (v_mfma_f32_16x16x32_bf16, verified per guide):
//   A-frag: lane l holds A[row = l&15][k = 8*(l>>4) + i], i = 0..7
//   B-frag: lane l holds B[k = 8*(l>>4) + i][col = l&15]
//   C/D   : lane l, reg i holds D[row = (l>>4)*4 + i][col = l&15]
// ---------------------------------------------------------------------------
__global__ __launch_bounds__(256) void main_mfma(
    const float* __restrict__ traj, const float* __restrict__ tgtc,
    const float* __restrict__ tgtg, const float* __restrict__ mu,
    const float* __restrict__ sg, const float* __restrict__ nz,
    const float* __restrict__ W1, const float* __restrict__ b1,
    const float* __restrict__ W2, const float* __restrict__ b2,
    const float* __restrict__ W3, const float* __restrict__ b3,
    float* __restrict__ pc, float* __restrict__ pg)
{
  const int tid = threadIdx.x;
  const int l = tid & 63;
  const int g = l >> 4;      // 16-lane group (k-chunk / row-quad selector)
  const int c = l & 15;      // column (and A-row) index
  const int w = tid >> 6;
  const int wid = blockIdx.x * 4 + w;

  __shared__ unsigned short hlds[4][16 * 40];   // per-wave 16x32 tile, stride 40
  unsigned short* lds = hlds[w];

  const f32x4 zro = {0.f, 0.f, 0.f, 0.f};

  // ===================== hoisted weight fragments =====================
  // W3 rows (8g+i) as float4 over k=0..3
  float w3e[8][4];
#pragma unroll
  for (int i = 0; i < 8; ++i) {
    float4 q = *reinterpret_cast<const float4*>(W3 + (8 * g + i) * 4);
    w3e[i][0] = q.x; w3e[i][1] = q.y; w3e[i][2] = q.z; w3e[i][3] = q.w;
  }

  // GEMM1 B-frags: W1p[k][col], k = kt*32+8g+i (zero-padded past 52), col = ct*16+c
  bf16x8 w1f[2][2];
#pragma unroll
  for (int kt = 0; kt < 2; ++kt) {
#pragma unroll
    for (int ct = 0; ct < 2; ++ct) {
#pragma unroll
      for (int i = 0; i < 8; ++i) {
        int kk = kt * 32 + 8 * g + i;
        float v = 0.f;
        if (kk < 52) v = W1[kk * 32 + ct * 16 + c];
        w1f[kt][ct][i] = (short)f2bf(v);
      }
    }
  }

  // GEMM2 B-frags: W2[k][col]
  bf16x8 w2f[2];
#pragma unroll
  for (int ct = 0; ct < 2; ++ct) {
#pragma unroll
    for (int i = 0; i < 8; ++i)
      w2f[ct][i] = (short)f2bf(W2[(8 * g + i) * 32 + ct * 16 + c]);
  }

  // head B-frag: W3 padded to 16 cols
  bf16x8 w3pf;
#pragma unroll
  for (int i = 0; i < 8; ++i) {
    float v = 0.f;
    if (c < 4) v = (c == 0) ? w3e[i][0] : (c == 1) ? w3e[i][1]
                 : (c == 2) ? w3e[i][2] : w3e[i][3];
    w3pf[i] = (short)f2bf(v);
  }

  // U_k frags: U_k[h][j] = W3[h][k] * W2[j][h];  h = 8g+i, j = ct*16+c
  float w2e[2][8];
#pragma unroll
  for (int ct = 0; ct < 2; ++ct) {
    float4 q0 = *reinterpret_cast<const float4*>(W2 + (ct * 16 + c) * 32 + 8 * g);
    float4 q1 = *reinterpret_cast<const float4*>(W2 + (ct * 16 + c) * 32 + 8 * g + 4);
    w2e[ct][0] = q0.x; w2e[ct][1] = q0.y; w2e[ct][2] = q0.z; w2e[ct][3] = q0.w;
    w2e[ct][4] = q1.x; w2e[ct][5] = q1.y; w2e[ct][6] = q1.z; w2e[ct][7] = q1.w;
  }
  bf16x8 uf[4][2];
#pragma unroll
  for (int k = 0; k < 4; ++k) {
#pragma unroll
    for (int i = 0; i < 8; ++i) {
      uf[k][0][i] = (short)f2bf(w3e[i][k] * w2e[0][i]);
      uf[k][1][i] = (short)f2bf(w3e[i][k] * w2e[1][i]);
    }
  }

  // V frags: V[j][x] = W1[x][j] (x < 36 else 0);  j = 8g+i, x = ct*16+c
  bf16x8 vf[3];
#pragma unroll
  for (int ct = 0; ct < 3; ++ct) {
    int x = ct * 16 + c;
    float4 v0 = {0,0,0,0}, v1 = {0,0,0,0};
    if (x < 36) {
      v0 = *reinterpret_cast<const float4*>(W1 + x * 32 + 8 * g);
      v1 = *reinterpret_cast<const float4*>(W1 + x * 32 + 8 * g + 4);
    }
    float va[8] = {v0.x, v0.y, v0.z, v0.w, v1.x, v1.y, v1.z, v1.w};
#pragma unroll
    for (int i = 0; i < 8; ++i) vf[ct][i] = (short)f2bf(va[i]);
  }

  const float b1c0 = b1[c], b1c1 = b1[c + 16];
  const float b2c0 = b2[c], b2c1 = b2[c + 16];
  const float b3v  = (c < 4) ? b3[c] : 0.f;

  // ===================== per-tile pipeline =====================
  float errc = 0.f, errg = 0.f;

#pragma unroll 1
  for (int jt = 0; jt < 2; ++jt) {
    const int tile = wid * 2 + jt;       // tile == b index
    const int s0 = tile * 16;
    const int srow = s0 + c;             // this lane's A-row sample

    // context value: every lane computes ctx[c]; lanes 0..15 serve as shfl src
    float ctxv;
    { int idx = tile * kCTX + c; ctxv = fmaf(sg[idx], nz[idx], mu[idx]); }

    // ---- A-frags of X = [traj | ctx | 0-pad], 16x64 ----
    const float* tr = traj + (size_t)srow * kXU;
    float4 q0 = *reinterpret_cast<const float4*>(tr + 8 * g);
    float4 q1 = *reinterpret_cast<const float4*>(tr + 8 * g + 4);
    bf16x8 a0;
    {
      float qa[8] = {q0.x, q0.y, q0.z, q0.w, q1.x, q1.y, q1.z, q1.w};
#pragma unroll
      for (int i = 0; i < 8; ++i) a0[i] = (short)f2bf(qa[i]);
    }
    float4 qt = {0,0,0,0};
    if (g == 0) qt = *reinterpret_cast<const float4*>(tr + 32);
    float qta[4] = {qt.x, qt.y, qt.z, qt.w};
    bf16x8 a1;
#pragma unroll
    for (int i = 0; i < 8; ++i) {
      int k = 32 + 8 * g + i;
      int ci = k - 36; ci = ci < 0 ? 0 : (ci > 15 ? 15 : ci);
      float cv = __shfl(ctxv, ci);               // convergent
      float v = 0.f;
      if (k < 52) v = (k < 36) ? qta[i & 3] : cv;
      a1[i] = (short)f2bf(v);
    }

    // ---- GEMM1: Z1 = X @ W1p  (+b1), keep mask bits ----
    f32x4 z1a0 = mfma16(a0, w1f[0][0], zro);
    z1a0 = mfma16(a1, w1f[1][0], z1a0);
    f32x4 z1a1 = mfma16(a0, w1f[0][1], zro);
    z1a1 = mfma16(a1, w1f[1][1], z1a1);
    unsigned m1bits = 0;
#pragma unroll
    for (int i = 0; i < 4; ++i) {
      float za = z1a0[i] + b1c0;
      float zb = z1a1[i] + b1c1;
      m1bits |= (za > 0.f ? 1u : 0u) << i;
      m1bits |= (zb > 0.f ? 1u : 0u) << (4 + i);
      lds[(4 * g + i) * 40 + c]      = f2bf(fmaxf(za, 0.f));
      lds[(4 * g + i) * 40 + 16 + c] = f2bf(fmaxf(zb, 0.f));
    }
    bf16x8 h1f = *reinterpret_cast<const bf16x8*>(lds + c * 40 + 8 * g);

    // ---- GEMM2: Z2 = H1 @ W2 (+b2) ----
    f32x4 z2a0 = mfma16(h1f, w2f[0], zro);
    f32x4 z2a1 = mfma16(h1f, w2f[1], zro);
#pragma unroll
    for (int i = 0; i < 4; ++i) { z2a0[i] += b2c0; z2a1[i] += b2c1; }
#pragma unroll
    for (int i = 0; i < 4; ++i) {
      lds[(4 * g + i) * 40 + c]      = f2bf(fmaxf(z2a0[i], 0.f));
      lds[(4 * g + i) * 40 + 16 + c] = f2bf(fmaxf(z2a1[i], 0.f));
    }
    bf16x8 h2f = *reinterpret_cast<const bf16x8*>(lds + c * 40 + 8 * g);

    // ---- head: P = H2 @ W3p (+b3), errc ----
    f32x4 pacc = mfma16(h2f, w3pf, zro);
    if (c < 4) {
#pragma unroll
      for (int i = 0; i < 4; ++i) {
        float p = pacc[i] + b3v;
        float d = p - tgtc[(size_t)(s0 + 4 * g + i) * kK + c];
        errc = fmaf(d, d, errc);
      }
    }

    // ---- M2 mask frag (0/1 bf16) ----
#pragma unroll
    for (int i = 0; i < 4; ++i) {
      lds[(4 * g + i) * 40 + c]      = (z2a0[i] > 0.f) ? (unsigned short)0x3F80 : (unsigned short)0;
      lds[(4 * g + i) * 40 + 16 + c] = (z2a1[i] > 0.f) ? (unsigned short)0x3F80 : (unsigned short)0;
    }
    bf16x8 m2f = *reinterpret_cast<const bf16x8*>(lds + c * 40 + 8 * g);

    // ---- Jacobian: per k: C_k = M2 @ U_k; T_k = m1 . C_k; J_k = T_k @ V ----
    const float* gp = tgtg + (size_t)s0 * (kK * kXU);
#pragma unroll
    for (int k = 0; k < 4; ++k) {
      f32x4 ck0 = mfma16(m2f, uf[k][0], zro);
      f32x4 ck1 = mfma16(m2f, uf[k][1], zro);
#pragma unroll
      for (int i = 0; i < 4; ++i) {
        float t0 = ((m1bits >> i) & 1u) ? ck0[i] : 0.f;
        float t1 = ((m1bits >> (4 + i)) & 1u) ? ck1[i] : 0.f;
        lds[(4 * g + i) * 40 + c]      = f2bf(t0);
        lds[(4 * g + i) * 40 + 16 + c] = f2bf(t1);
      }
      bf16x8 tf = *reinterpret_cast<const bf16x8*>(lds + c * 40 + 8 * g);
      f32x4 ja[3];
      ja[0] = mfma16(tf, vf[0], zro);
      ja[1] = mfma16(tf, vf[1], zro);
      ja[2] = mfma16(tf, vf[2], zro);
#pragma unroll
      for (int ct = 0; ct < 3; ++ct) {
        int col = ct * 16 + c;
        if (col < kXU) {
#pragma unroll
          for (int i = 0; i < 4; ++i) {
            float d = ja[ct][i] - gp[(size_t)(4 * g + i) * (kK * kXU) + k * kXU + col];
            errg = fmaf(d, d, errg);
          }
        }
      }
    }
  }

  // ---- wave reduction (deterministic), one partial per wave ----
#pragma unroll
  for (int off = 32; off > 0; off >>= 1) {
    errc += __shfl_down(errc, off);
    errg += __shfl_down(errg, off);
  }
  if (l == 0) { pc[wid] = errc; pg[wid] = errg; }
}

// ---------------------------------------------------------------------------
// finalize: reduce 512 kl + 4096 pc + 4096 pg partials, write loss
// ---------------------------------------------------------------------------
__global__ __launch_bounds__(256) void finalize_kernel(
    const float* __restrict__ ws, float* __restrict__ out)
{
  const int tid = threadIdx.x;
  float kl = ws[tid] + ws[tid + 256];
  float cs = 0.f, gs = 0.f;
#pragma unroll
  for (int i = 0; i < 16; ++i) {
    cs += ws[512 + tid + i * 256];
    gs += ws[512 + 4096 + tid + i * 256];
  }
  __shared__ float rk[256], rc[256], rg[256];
  rk[tid] = kl; rc[tid] = cs; rg[tid] = gs;
  __syncthreads();
  for (int off = 128; off > 0; off >>= 1) {
    if (tid < off) {
      rk[tid] += rk[tid + off];
      rc[tid] += rc[tid + off];
      rg[tid] += rg[tid + off];
    }
    __syncthreads();
  }
  if (tid == 0) {
    out[0] = rc[0] / (float)(kBT * kK)
           + rg[0] / ((float)kBT * (float)(kK * kXU))
           + rk[0] / (float)(kB * kCTX);
  }
}

// ---------------------------------------------------------------------------
extern "C" void kernel_launch(void* const* d_in, const int* in_sizes, int n_in,
                              void* d_out, int out_size, void* d_ws, size_t ws_size,
                              hipStream_t stream)
{
  const float* traj = (const float*)d_in[0];
  const float* tgtc = (const float*)d_in[1];
  const float* tgtg = (const float*)d_in[2];
  const float* mu   = (const float*)d_in[3];
  const float* sg   = (const float*)d_in[4];
  const float* nz   = (const float*)d_in[5];
  const float* W1   = (const float*)d_in[6];
  const float* b1   = (const float*)d_in[7];
  const float* W2   = (const float*)d_in[8];
  const float* b2   = (const float*)d_in[9];
  const float* W3   = (const float*)d_in[10];
  const float* b3   = (const float*)d_in[11];

  float* out = (float*)d_out;
  float* ws  = (float*)d_ws;
  float* kl_part = ws;            // [0, 512)
  float* pc      = ws + 512;      // [512, 4608)
  float* pg      = ws + 4608;     // [4608, 8704)

  ctx_kl_kernel<<<kNC, 256, 0, stream>>>(mu, sg, nz, out + 1, kl_part);
  main_mfma<<<kMainBlocks, 256, 0, stream>>>(traj, tgtc, tgtg, mu, sg, nz,
                                             W1, b1, W2, b2, W3, b3, pc, pg);
  finalize_kernel<<<1, 256, 0, stream>>>(ws, out);
}

// Round 4
// 41.430 us; speedup vs baseline: 6.2264x; 1.0186x over previous
//
#include <hip/hip_runtime.h>
#include <math.h>

typedef __attribute__((ext_vector_type(8))) short bf16x8;
typedef __attribute__((ext_vector_type(4))) float f32x4;

namespace {
constexpr int kB   = 8192;
constexpr int kT   = 16;
constexpr int kXU  = 36;
constexpr int kCTX = 16;
constexpr int kK   = 4;
constexpr int kBT  = kB * kT;            // 131072 samples
constexpr int kMainBlocks = 1024;        // 4 waves/block -> 4096 waves, 2 tiles/wave
constexpr int kNC = (kB * kCTX) / 256;   // 512 blocks for ctx/kl
}

__device__ __forceinline__ unsigned short f2bf(float f) {
  union { float f; unsigned u; } v; v.f = f;
  unsigned u = v.u + 0x7FFFu + ((v.u >> 16) & 1u);   // RNE
  return (unsigned short)(u >> 16);
}

// pack two f32 -> (hi<<16)|lo bf16 pair, RNE, single instruction
__device__ __forceinline__ unsigned cvtpk(float lo, float hi) {
  unsigned r;
  asm("v_cvt_pk_bf16_f32 %0, %1, %2" : "=v"(r) : "v"(lo), "v"(hi));
  return r;
}

union Frag { bf16x8 v; unsigned u[4]; };

__device__ __forceinline__ f32x4 mfma16(bf16x8 a, bf16x8 b, f32x4 c) {
  return __builtin_amdgcn_mfma_f32_16x16x32_bf16(a, b, c, 0, 0, 0);
}

// ---------------------------------------------------------------------------
// context = mu + sigma*noise  (written to d_out+1), plus per-block KL partials
// ---------------------------------------------------------------------------
__global__ __launch_bounds__(256) void ctx_kl_kernel(
    const float* __restrict__ mu, const float* __restrict__ sg,
    const float* __restrict__ nz, float* __restrict__ ctx_out,
    float* __restrict__ kl_part)
{
  const int tid = threadIdx.x;
  const int i = blockIdx.x * 256 + tid;
  float m = mu[i], s = sg[i], n = nz[i];
  ctx_out[i] = fmaf(s, n, m);
  float kl = 0.5f * (s * s + m * m) - logf(s) - 0.5f;

  __shared__ float red[256];
  red[tid] = kl;
  __syncthreads();
  for (int off = 128; off > 0; off >>= 1) {
    if (tid < off) red[tid] += red[tid + off];
    __syncthreads();
  }
  if (tid == 0) kl_part[blockIdx.x] = red[0];
}

// ---------------------------------------------------------------------------
// main: transposed-GEMM MFMA pipeline, zero LDS.
//
// All GEMMs computed as D^T = W^T @ Act^T with the weight (A-operand) rows
// PERMUTED at load time: first-half MFMA computes output feature
// f = 8*(r>>2)+(r&3) at row r, second-half f+4. Then lane (g,c)'s D regs
// hold features {8g+i} / {8g+4+i} of sample c — exactly the B-frag layout
// (elem i = k=8g+i, col=c) of the next GEMM. Activations never leave the
// lane: no LDS, no shuffles.
//
// MFMA layouts (v_mfma_f32_16x16x32_bf16):
//   A-frag: lane l holds A[row=l&15][k=8*(l>>4)+i]
//   B-frag: lane l holds B[k=8*(l>>4)+i][col=l&15]
//   D     : lane l reg i holds D[row=4*(l>>4)+i][col=l&15]
// ---------------------------------------------------------------------------
__global__ __launch_bounds__(256, 3) void main_mfma(
    const float* __restrict__ traj, const float* __restrict__ tgtc,
    const float* __restrict__ tgtg, const float* __restrict__ mu,
    const float* __restrict__ sg, const float* __restrict__ nz,
    const float* __restrict__ W1, const float* __restrict__ b1,
    const float* __restrict__ W2, const float* __restrict__ b2,
    const float* __restrict__ W3, const float* __restrict__ b3,
    float* __restrict__ pc, float* __restrict__ pg)
{
  const int tid = threadIdx.x;
  const int l = tid & 63;
  const int g = l >> 4;       // k-chunk group
  const int c = l & 15;       // sample column / A-row
  const int wid = blockIdx.x * 4 + (tid >> 6);
  const int pa = 8 * (c >> 2) + (c & 3);   // permuted feature for A rows (1st half)
  const int pb = pa + 4;                   // 2nd half

  const f32x4 zro = {0.f, 0.f, 0.f, 0.f};

  // ===================== prologue: weight fragments =====================
  // GEMM1 A-frags: W1p^T, rows permuted. elem i = W1[kk][pa/pb], kk=kt*32+8g+i
  Frag w1a[2], w1b[2];
#pragma unroll
  for (int kt = 0; kt < 2; ++kt) {
    float va[8], vb[8];
#pragma unroll
    for (int i = 0; i < 8; ++i) {
      int kk = kt * 32 + 8 * g + i;
      va[i] = (kk < 52) ? W1[kk * 32 + pa] : 0.f;
      vb[i] = (kk < 52) ? W1[kk * 32 + pb] : 0.f;
    }
#pragma unroll
    for (int q = 0; q < 4; ++q) {
      w1a[kt].u[q] = cvtpk(va[2 * q], va[2 * q + 1]);
      w1b[kt].u[q] = cvtpk(vb[2 * q], vb[2 * q + 1]);
    }
  }

  // GEMM2 A-frags: W2^T rows permuted. elem i = W2[8g+i][pa/pb]
  Frag w2af, w2bf;
  {
    float va[8], vb[8];
#pragma unroll
    for (int i = 0; i < 8; ++i) {
      va[i] = W2[(8 * g + i) * 32 + pa];
      vb[i] = W2[(8 * g + i) * 32 + pb];
    }
#pragma unroll
    for (int q = 0; q < 4; ++q) {
      w2af.u[q] = cvtpk(va[2 * q], va[2 * q + 1]);
      w2bf.u[q] = cvtpk(vb[2 * q], vb[2 * q + 1]);
    }
  }

  // head A-frag: W3^T natural rows (we only consume rows 0-3 -> g==0 regs)
  Frag w3f;
  {
    float va[8];
#pragma unroll
    for (int i = 0; i < 8; ++i)
      va[i] = (c < 4) ? W3[(8 * g + i) * 4 + c] : 0.f;
#pragma unroll
    for (int q = 0; q < 4; ++q) w3f.u[q] = cvtpk(va[2 * q], va[2 * q + 1]);
  }

  // U_k^T A-frags: U_k^T[j][h] = W3[h][k]*W2[j][h], rows j permuted.
  float w3v[8][4];
#pragma unroll
  for (int i = 0; i < 8; ++i) {
    float4 q = *reinterpret_cast<const float4*>(W3 + (8 * g + i) * 4);
    w3v[i][0] = q.x; w3v[i][1] = q.y; w3v[i][2] = q.z; w3v[i][3] = q.w;
  }
  float w2ra[8], w2rb[8];
  {
    float4 a0 = *reinterpret_cast<const float4*>(W2 + pa * 32 + 8 * g);
    float4 a1 = *reinterpret_cast<const float4*>(W2 + pa * 32 + 8 * g + 4);
    float4 b0 = *reinterpret_cast<const float4*>(W2 + pb * 32 + 8 * g);
    float4 b1q = *reinterpret_cast<const float4*>(W2 + pb * 32 + 8 * g + 4);
    w2ra[0]=a0.x; w2ra[1]=a0.y; w2ra[2]=a0.z; w2ra[3]=a0.w;
    w2ra[4]=a1.x; w2ra[5]=a1.y; w2ra[6]=a1.z; w2ra[7]=a1.w;
    w2rb[0]=b0.x; w2rb[1]=b0.y; w2rb[2]=b0.z; w2rb[3]=b0.w;
    w2rb[4]=b1q.x; w2rb[5]=b1q.y; w2rb[6]=b1q.z; w2rb[7]=b1q.w;
  }
  Frag uka[4], ukb[4];
#pragma unroll
  for (int k = 0; k < 4; ++k) {
#pragma unroll
    for (int q = 0; q < 4; ++q) {
      uka[k].u[q] = cvtpk(w3v[2*q][k] * w2ra[2*q], w3v[2*q+1][k] * w2ra[2*q+1]);
      ukb[k].u[q] = cvtpk(w3v[2*q][k] * w2rb[2*q], w3v[2*q+1][k] * w2rb[2*q+1]);
    }
  }

  // J A-frags: rows x natural (output stays in D layout for float4 target cmp)
  Frag w1vf[3];
#pragma unroll
  for (int jj = 0; jj < 3; ++jj) {
    int x = 16 * jj + c;
    float va[8] = {0,0,0,0,0,0,0,0};
    if (x < kXU) {
      float4 p0 = *reinterpret_cast<const float4*>(W1 + x * 32 + 8 * g);
      float4 p1 = *reinterpret_cast<const float4*>(W1 + x * 32 + 8 * g + 4);
      va[0]=p0.x; va[1]=p0.y; va[2]=p0.z; va[3]=p0.w;
      va[4]=p1.x; va[5]=p1.y; va[6]=p1.z; va[7]=p1.w;
    }
#pragma unroll
    for (int q = 0; q < 4; ++q) w1vf[jj].u[q] = cvtpk(va[2*q], va[2*q+1]);
  }

  // biases (per-lane feature sets)
  float b1l[4], b1h[4], b2l[4], b2h[4], b3a[4];
  {
    float4 q0 = *reinterpret_cast<const float4*>(b1 + 8 * g);
    float4 q1 = *reinterpret_cast<const float4*>(b1 + 8 * g + 4);
    b1l[0]=q0.x; b1l[1]=q0.y; b1l[2]=q0.z; b1l[3]=q0.w;
    b1h[0]=q1.x; b1h[1]=q1.y; b1h[2]=q1.z; b1h[3]=q1.w;
    float4 r0 = *reinterpret_cast<const float4*>(b2 + 8 * g);
    float4 r1 = *reinterpret_cast<const float4*>(b2 + 8 * g + 4);
    b2l[0]=r0.x; b2l[1]=r0.y; b2l[2]=r0.z; b2l[3]=r0.w;
    b2h[0]=r1.x; b2h[1]=r1.y; b2h[2]=r1.z; b2h[3]=r1.w;
    float4 s0q = *reinterpret_cast<const float4*>(b3);
    b3a[0]=s0q.x; b3a[1]=s0q.y; b3a[2]=s0q.z; b3a[3]=s0q.w;
  }

  // ===================== per-tile pipeline =====================
  float errc = 0.f, errg = 0.f;

#pragma unroll 1
  for (int jt = 0; jt < 2; ++jt) {
    const int tile = wid * 2 + jt;       // tile == b index
    const int s0 = tile * 16;

    float ctxv;
    { int idx = tile * kCTX + c; ctxv = fmaf(sg[idx], nz[idx], mu[idx]); }

    // ---- B-frags of X^T (lane (g,c) elem i = X[c][8g+i]) ----
    const float* tr = traj + (size_t)(s0 + c) * kXU;
    float4 q0 = *reinterpret_cast<const float4*>(tr + 8 * g);
    float4 q1 = *reinterpret_cast<const float4*>(tr + 8 * g + 4);
    Frag x0;
    x0.u[0] = cvtpk(q0.x, q0.y); x0.u[1] = cvtpk(q0.z, q0.w);
    x0.u[2] = cvtpk(q1.x, q1.y); x0.u[3] = cvtpk(q1.z, q1.w);
    float4 qt = (g == 0) ? *reinterpret_cast<const float4*>(tr + 32)
                         : make_float4(0.f, 0.f, 0.f, 0.f);
    float qta[4] = {qt.x, qt.y, qt.z, qt.w};
    float va1[8];
#pragma unroll
    for (int i = 0; i < 8; ++i) {
      int k = 32 + 8 * g + i;
      int ci = k - 36; ci = ci < 0 ? 0 : (ci > 15 ? 15 : ci);
      float cv = __shfl(ctxv, ci);               // convergent
      va1[i] = (k < 52) ? ((k < 36) ? qta[i & 3] : cv) : 0.f;
    }
    Frag x1;
    x1.u[0] = cvtpk(va1[0], va1[1]); x1.u[1] = cvtpk(va1[2], va1[3]);
    x1.u[2] = cvtpk(va1[4], va1[5]); x1.u[3] = cvtpk(va1[6], va1[7]);

    // ---- GEMM1: Z1^T = W1p^T @ X^T ----
    f32x4 d1a = mfma16(w1a[0].v, x0.v, zro);
    d1a = mfma16(w1a[1].v, x1.v, d1a);
    f32x4 d1b = mfma16(w1b[0].v, x0.v, zro);
    d1b = mfma16(w1b[1].v, x1.v, d1b);

    float m1a[4], m1b[4], h1lo[4], h1hi[4];
#pragma unroll
    for (int i = 0; i < 4; ++i) {
      float za = d1a[i] + b1l[i];
      float zb = d1b[i] + b1h[i];
      m1a[i] = (za > 0.f) ? 1.f : 0.f;
      m1b[i] = (zb > 0.f) ? 1.f : 0.f;
      h1lo[i] = fmaxf(za, 0.f);
      h1hi[i] = fmaxf(zb, 0.f);
    }
    Frag h1f;
    h1f.u[0] = cvtpk(h1lo[0], h1lo[1]); h1f.u[1] = cvtpk(h1lo[2], h1lo[3]);
    h1f.u[2] = cvtpk(h1hi[0], h1hi[1]); h1f.u[3] = cvtpk(h1hi[2], h1hi[3]);

    // ---- GEMM2: Z2^T = W2^T @ H1^T ----
    f32x4 d2a = mfma16(w2af.v, h1f.v, zro);
    f32x4 d2b = mfma16(w2bf.v, h1f.v, zro);
    float h2lo[4], h2hi[4];
    unsigned m2lo[4], m2hi[4];
#pragma unroll
    for (int i = 0; i < 4; ++i) {
      float za = d2a[i] + b2l[i];
      float zb = d2b[i] + b2h[i];
      m2lo[i] = (za > 0.f) ? 0x3F80u : 0u;
      m2hi[i] = (zb > 0.f) ? 0x3F80u : 0u;
      h2lo[i] = fmaxf(za, 0.f);
      h2hi[i] = fmaxf(zb, 0.f);
    }
    Frag h2f;
    h2f.u[0] = cvtpk(h2lo[0], h2lo[1]); h2f.u[1] = cvtpk(h2lo[2], h2lo[3]);
    h2f.u[2] = cvtpk(h2hi[0], h2hi[1]); h2f.u[3] = cvtpk(h2hi[2], h2hi[3]);
    Frag m2f;
    m2f.u[0] = m2lo[0] | (m2lo[1] << 16); m2f.u[1] = m2lo[2] | (m2lo[3] << 16);
    m2f.u[2] = m2hi[0] | (m2hi[1] << 16); m2f.u[3] = m2hi[2] | (m2hi[3] << 16);

    // ---- head: P^T = W3^T @ H2^T, errc (g==0 lanes hold k=0..3) ----
    f32x4 pacc = mfma16(w3f.v, h2f.v, zro);
    if (g == 0) {
      float4 t4 = *reinterpret_cast<const float4*>(tgtc + (size_t)(s0 + c) * kK);
      float tv[4] = {t4.x, t4.y, t4.z, t4.w};
#pragma unroll
      for (int i = 0; i < 4; ++i) {
        float d = (pacc[i] + b3a[i]) - tv[i];
        errc = fmaf(d, d, errc);
      }
    }

    // ---- Jacobian: per k: C_k^T = U_k^T @ M2^T; T^T = m1.*C; J^T = W1x @ T^T
    const float* gpb = tgtg + (size_t)(s0 + c) * (kK * kXU);
#pragma unroll
    for (int k = 0; k < 4; ++k) {
      f32x4 ca = mfma16(uka[k].v, m2f.v, zro);
      f32x4 cb = mfma16(ukb[k].v, m2f.v, zro);
      float ta[4], tb[4];
#pragma unroll
      for (int i = 0; i < 4; ++i) {
        ta[i] = ca[i] * m1a[i];
        tb[i] = cb[i] * m1b[i];
      }
      Frag tf;
      tf.u[0] = cvtpk(ta[0], ta[1]); tf.u[1] = cvtpk(ta[2], ta[3]);
      tf.u[2] = cvtpk(tb[0], tb[1]); tf.u[3] = cvtpk(tb[2], tb[3]);
#pragma unroll
      for (int jj = 0; jj < 3; ++jj) {
        f32x4 j4 = mfma16(w1vf[jj].v, tf.v, zro);
        if (jj < 2 || g == 0) {   // jj==2 valid only for x=32..35 (g==0)
          float4 t4 = *reinterpret_cast<const float4*>(gpb + k * kXU + jj * 16 + 4 * g);
          float tv[4] = {t4.x, t4.y, t4.z, t4.w};
#pragma unroll
          for (int i = 0; i < 4; ++i) {
            float d = j4[i] - tv[i];
            errg = fmaf(d, d, errg);
          }
        }
      }
    }
  }

  // ---- wave reduction (deterministic), one partial pair per wave ----
#pragma unroll
  for (int off = 32; off > 0; off >>= 1) {
    errc += __shfl_down(errc, off);
    errg += __shfl_down(errg, off);
  }
  if (l == 0) { pc[wid] = errc; pg[wid] = errg; }
}

// ---------------------------------------------------------------------------
// finalize: reduce 512 kl + 4096 pc + 4096 pg partials, write loss
// ---------------------------------------------------------------------------
__global__ __launch_bounds__(256) void finalize_kernel(
    const float* __restrict__ ws, float* __restrict__ out)
{
  const int tid = threadIdx.x;
  float kl = ws[tid] + ws[tid + 256];
  float cs = 0.f, gs = 0.f;
#pragma unroll
  for (int i = 0; i < 16; ++i) {
    cs += ws[512 + tid + i * 256];
    gs += ws[512 + 4096 + tid + i * 256];
  }
  __shared__ float rk[256], rc[256], rg[256];
  rk[tid] = kl; rc[tid] = cs; rg[tid] = gs;
  __syncthreads();
  for (int off = 128; off > 0; off >>= 1) {
    if (tid < off) {
      rk[tid] += rk[tid + off];
      rc[tid] += rc[tid + off];
      rg[tid] += rg[tid + off];
    }
    __syncthreads();
  }
  if (tid == 0) {
    out[0] = rc[0] / (float)(kBT * kK)
           + rg[0] / ((float)kBT * (float)(kK * kXU))
           + rk[0] / (float)(kB * kCTX);
  }
}

// ---------------------------------------------------------------------------
extern "C" void kernel_launch(void* const* d_in, const int* in_sizes, int n_in,
                              void* d_out, int out_size, void* d_ws, size_t ws_size,
                              hipStream_t stream)
{
  const float* traj = (const float*)d_in[0];
  const float* tgtc = (const float*)d_in[1];
  const float* tgtg = (const float*)d_in[2];
  const float* mu   = (const float*)d_in[3];
  const float* sg   = (const float*)d_in[4];
  const float* nz   = (const float*)d_in[5];
  const float* W1   = (const float*)d_in[6];
  const float* b1   = (const float*)d_in[7];
  const float* W2   = (const float*)d_in[8];
  const float* b2   = (const float*)d_in[9];
  const float* W3   = (const float*)d_in[10];
  const float* b3   = (const float*)d_in[11];

  float* out = (float*)d_out;
  float* ws  = (float*)d_ws;
  float* kl_part = ws;            // [0, 512)
  float* pc      = ws + 512;      // [512, 4608)
  float* pg      = ws + 4608;     // [4608, 8704)

  ctx_kl_kernel<<<kNC, 256, 0, stream>>>(mu, sg, nz, out + 1, kl_part);
  main_mfma<<<kMainBlocks, 256, 0, stream>>>(traj, tgtc, tgtg, mu, sg, nz,
                                             W1, b1, W2, b2, W3, b3, pc, pg);
  finalize_kernel<<<1, 256, 0, stream>>>(ws, out);
}

// Round 6
// 41.296 us; speedup vs baseline: 6.2466x; 1.0033x over previous
//
#include <hip/hip_runtime.h>
#include <math.h>

typedef __attribute__((ext_vector_type(8))) short bf16x8;
typedef __attribute__((ext_vector_type(4))) float f32x4;

namespace {
constexpr int kB   = 8192;
constexpr int kT   = 16;
constexpr int kXU  = 36;
constexpr int kCTX = 16;
constexpr int kK   = 4;
constexpr int kBT  = kB * kT;            // 131072 samples
constexpr int kMainBlocks = 1024;        // 4 waves/block -> 4096 waves, 2 tiles/wave
constexpr int kNC = (kB * kCTX) / 256;   // 512 blocks for ctx/kl
}

__device__ __forceinline__ unsigned short f2bf(float f) {
  union { float f; unsigned u; } v; v.f = f;
  unsigned u = v.u + 0x7FFFu + ((v.u >> 16) & 1u);   // RNE
  return (unsigned short)(u >> 16);
}

// pack two f32 -> (hi<<16)|lo bf16 pair, RNE, single instruction
__device__ __forceinline__ unsigned cvtpk(float lo, float hi) {
  unsigned r;
  asm("v_cvt_pk_bf16_f32 %0, %1, %2" : "=v"(r) : "v"(lo), "v"(hi));
  return r;
}

union Frag { bf16x8 v; unsigned u[4]; };

__device__ __forceinline__ f32x4 mfma16(bf16x8 a, bf16x8 b, f32x4 c) {
  return __builtin_amdgcn_mfma_f32_16x16x32_bf16(a, b, c, 0, 0, 0);
}

// ---------------------------------------------------------------------------
// context = mu + sigma*noise  (written to d_out+1), plus per-block KL partials
// ---------------------------------------------------------------------------
__global__ __launch_bounds__(256) void ctx_kl_kernel(
    const float* __restrict__ mu, const float* __restrict__ sg,
    const float* __restrict__ nz, float* __restrict__ ctx_out,
    float* __restrict__ kl_part)
{
  const int tid = threadIdx.x;
  const int i = blockIdx.x * 256 + tid;
  float m = mu[i], s = sg[i], n = nz[i];
  ctx_out[i] = fmaf(s, n, m);
  float kl = 0.5f * (s * s + m * m) - logf(s) - 0.5f;

  __shared__ float red[256];
  red[tid] = kl;
  __syncthreads();
  for (int off = 128; off > 0; off >>= 1) {
    if (tid < off) red[tid] += red[tid + off];
    __syncthreads();
  }
  if (tid == 0) kl_part[blockIdx.x] = red[0];
}

// ---------------------------------------------------------------------------
// main: transposed-GEMM MFMA pipeline, zero LDS. Round-3 structure verbatim;
// the ONLY change: the 8 always-valid tgtg float4 loads are hoisted to the
// top of the tile body (issue-early MLP) into statically-indexed registers.
//
// MFMA layouts (v_mfma_f32_16x16x32_bf16):
//   A-frag: lane l holds A[row=l&15][k=8*(l>>4)+i]
//   B-frag: lane l holds B[k=8*(l>>4)+i][col=l&15]
//   D     : lane l reg i holds D[row=4*(l>>4)+i][col=l&15]
// Weight A-operand rows are permuted (pa=8*(c>>2)+(c&3), pb=pa+4) so each
// GEMM's D registers land exactly in the next GEMM's B-frag element order.
// ---------------------------------------------------------------------------
__global__ __launch_bounds__(256, 3) void main_mfma(
    const float* __restrict__ traj, const float* __restrict__ tgtc,
    const float* __restrict__ tgtg, const float* __restrict__ mu,
    const float* __restrict__ sg, const float* __restrict__ nz,
    const float* __restrict__ W1, const float* __restrict__ b1,
    const float* __restrict__ W2, const float* __restrict__ b2,
    const float* __restrict__ W3, const float* __restrict__ b3,
    float* __restrict__ pc, float* __restrict__ pg)
{
  const int tid = threadIdx.x;
  const int l = tid & 63;
  const int g = l >> 4;       // k-chunk group
  const int c = l & 15;       // sample column / A-row
  const int wid = blockIdx.x * 4 + (tid >> 6);
  const int pa = 8 * (c >> 2) + (c & 3);   // permuted feature for A rows (1st half)
  const int pb = pa + 4;                   // 2nd half

  const f32x4 zro = {0.f, 0.f, 0.f, 0.f};

  // ===================== prologue: weight fragments =====================
  Frag w1a[2], w1b[2];
#pragma unroll
  for (int kt = 0; kt < 2; ++kt) {
    float va[8], vb[8];
#pragma unroll
    for (int i = 0; i < 8; ++i) {
      int kk = kt * 32 + 8 * g + i;
      va[i] = (kk < 52) ? W1[kk * 32 + pa] : 0.f;
      vb[i] = (kk < 52) ? W1[kk * 32 + pb] : 0.f;
    }
#pragma unroll
    for (int q = 0; q < 4; ++q) {
      w1a[kt].u[q] = cvtpk(va[2 * q], va[2 * q + 1]);
      w1b[kt].u[q] = cvtpk(vb[2 * q], vb[2 * q + 1]);
    }
  }

  Frag w2af, w2bf;
  {
    float va[8], vb[8];
#pragma unroll
    for (int i = 0; i < 8; ++i) {
      va[i] = W2[(8 * g + i) * 32 + pa];
      vb[i] = W2[(8 * g + i) * 32 + pb];
    }
#pragma unroll
    for (int q = 0; q < 4; ++q) {
      w2af.u[q] = cvtpk(va[2 * q], va[2 * q + 1]);
      w2bf.u[q] = cvtpk(vb[2 * q], vb[2 * q + 1]);
    }
  }

  Frag w3f;
  {
    float va[8];
#pragma unroll
    for (int i = 0; i < 8; ++i)
      va[i] = (c < 4) ? W3[(8 * g + i) * 4 + c] : 0.f;
#pragma unroll
    for (int q = 0; q < 4; ++q) w3f.u[q] = cvtpk(va[2 * q], va[2 * q + 1]);
  }

  // U_k^T A-frags: U_k^T[j][h] = W3[h][k]*W2[j][h], rows j permuted.
  float w3v[8][4];
#pragma unroll
  for (int i = 0; i < 8; ++i) {
    float4 q = *reinterpret_cast<const float4*>(W3 + (8 * g + i) * 4);
    w3v[i][0] = q.x; w3v[i][1] = q.y; w3v[i][2] = q.z; w3v[i][3] = q.w;
  }
  float w2ra[8], w2rb[8];
  {
    float4 a0 = *reinterpret_cast<const float4*>(W2 + pa * 32 + 8 * g);
    float4 a1 = *reinterpret_cast<const float4*>(W2 + pa * 32 + 8 * g + 4);
    float4 b0 = *reinterpret_cast<const float4*>(W2 + pb * 32 + 8 * g);
    float4 b1q = *reinterpret_cast<const float4*>(W2 + pb * 32 + 8 * g + 4);
    w2ra[0]=a0.x; w2ra[1]=a0.y; w2ra[2]=a0.z; w2ra[3]=a0.w;
    w2ra[4]=a1.x; w2ra[5]=a1.y; w2ra[6]=a1.z; w2ra[7]=a1.w;
    w2rb[0]=b0.x; w2rb[1]=b0.y; w2rb[2]=b0.z; w2rb[3]=b0.w;
    w2rb[4]=b1q.x; w2rb[5]=b1q.y; w2rb[6]=b1q.z; w2rb[7]=b1q.w;
  }
  Frag uka[4], ukb[4];
#pragma unroll
  for (int k = 0; k < 4; ++k) {
#pragma unroll
    for (int q = 0; q < 4; ++q) {
      uka[k].u[q] = cvtpk(w3v[2*q][k] * w2ra[2*q], w3v[2*q+1][k] * w2ra[2*q+1]);
      ukb[k].u[q] = cvtpk(w3v[2*q][k] * w2rb[2*q], w3v[2*q+1][k] * w2rb[2*q+1]);
    }
  }

  // J A-frags: rows x natural (output stays in D layout for float4 target cmp)
  Frag w1vf[3];
#pragma unroll
  for (int jj = 0; jj < 3; ++jj) {
    int x = 16 * jj + c;
    float va[8] = {0,0,0,0,0,0,0,0};
    if (x < kXU) {
      float4 p0 = *reinterpret_cast<const float4*>(W1 + x * 32 + 8 * g);
      float4 p1 = *reinterpret_cast<const float4*>(W1 + x * 32 + 8 * g + 4);
      va[0]=p0.x; va[1]=p0.y; va[2]=p0.z; va[3]=p0.w;
      va[4]=p1.x; va[5]=p1.y; va[6]=p1.z; va[7]=p1.w;
    }
#pragma unroll
    for (int q = 0; q < 4; ++q) w1vf[jj].u[q] = cvtpk(va[2*q], va[2*q+1]);
  }

  // biases (per-lane feature sets)
  float b1l[4], b1h[4], b2l[4], b2h[4], b3a[4];
  {
    float4 q0 = *reinterpret_cast<const float4*>(b1 + 8 * g);
    float4 q1 = *reinterpret_cast<const float4*>(b1 + 8 * g + 4);
    b1l[0]=q0.x; b1l[1]=q0.y; b1l[2]=q0.z; b1l[3]=q0.w;
    b1h[0]=q1.x; b1h[1]=q1.y; b1h[2]=q1.z; b1h[3]=q1.w;
    float4 r0 = *reinterpret_cast<const float4*>(b2 + 8 * g);
    float4 r1 = *reinterpret_cast<const float4*>(b2 + 8 * g + 4);
    b2l[0]=r0.x; b2l[1]=r0.y; b2l[2]=r0.z; b2l[3]=r0.w;
    b2h[0]=r1.x; b2h[1]=r1.y; b2h[2]=r1.z; b2h[3]=r1.w;
    float4 s0q = *reinterpret_cast<const float4*>(b3);
    b3a[0]=s0q.x; b3a[1]=s0q.y; b3a[2]=s0q.z; b3a[3]=s0q.w;
  }

  // ===================== per-tile pipeline =====================
  float errc = 0.f, errg = 0.f;

#pragma unroll 1
  for (int jt = 0; jt < 2; ++jt) {
    const int tile = wid * 2 + jt;       // tile == b index
    const int s0 = tile * 16;

    float ctxv;
    { int idx = tile * kCTX + c; ctxv = fmaf(sg[idx], nz[idx], mu[idx]); }

    // ---- traj loads ----
    const float* tr = traj + (size_t)(s0 + c) * kXU;
    float4 q0 = *reinterpret_cast<const float4*>(tr + 8 * g);
    float4 q1 = *reinterpret_cast<const float4*>(tr + 8 * g + 4);

    // ---- HOISTED tgtg loads (always-valid 8 float4s; issue-early so the
    //      whole MLP/Jacobian chain runs under this stream) ----
    const float* gpb = tgtg + (size_t)(s0 + c) * (kK * kXU);
    float4 tg0[4], tg1[4];
#pragma unroll
    for (int k = 0; k < 4; ++k) {
      tg0[k] = *reinterpret_cast<const float4*>(gpb + k * kXU + 4 * g);
      tg1[k] = *reinterpret_cast<const float4*>(gpb + k * kXU + 16 + 4 * g);
    }

    // ---- B-frags of X^T (lane (g,c) elem i = X[c][8g+i]) ----
    Frag x0;
    x0.u[0] = cvtpk(q0.x, q0.y); x0.u[1] = cvtpk(q0.z, q0.w);
    x0.u[2] = cvtpk(q1.x, q1.y); x0.u[3] = cvtpk(q1.z, q1.w);
    float4 qt = (g == 0) ? *reinterpret_cast<const float4*>(tr + 32)
                         : make_float4(0.f, 0.f, 0.f, 0.f);
    float qta[4] = {qt.x, qt.y, qt.z, qt.w};
    float va1[8];
#pragma unroll
    for (int i = 0; i < 8; ++i) {
      int k = 32 + 8 * g + i;
      int ci = k - 36; ci = ci < 0 ? 0 : (ci > 15 ? 15 : ci);
      float cv = __shfl(ctxv, ci);               // convergent
      va1[i] = (k < 52) ? ((k < 36) ? qta[i & 3] : cv) : 0.f;
    }
    Frag x1;
    x1.u[0] = cvtpk(va1[0], va1[1]); x1.u[1] = cvtpk(va1[2], va1[3]);
    x1.u[2] = cvtpk(va1[4], va1[5]); x1.u[3] = cvtpk(va1[6], va1[7]);

    // ---- GEMM1: Z1^T = W1p^T @ X^T ----
    f32x4 d1a = mfma16(w1a[0].v, x0.v, zro);
    d1a = mfma16(w1a[1].v, x1.v, d1a);
    f32x4 d1b = mfma16(w1b[0].v, x0.v, zro);
    d1b = mfma16(w1b[1].v, x1.v, d1b);

    float m1a[4], m1b[4], h1lo[4], h1hi[4];
#pragma unroll
    for (int i = 0; i < 4; ++i) {
      float za = d1a[i] + b1l[i];
      float zb = d1b[i] + b1h[i];
      m1a[i] = (za > 0.f) ? 1.f : 0.f;
      m1b[i] = (zb > 0.f) ? 1.f : 0.f;
      h1lo[i] = fmaxf(za, 0.f);
      h1hi[i] = fmaxf(zb, 0.f);
    }
    Frag h1f;
    h1f.u[0] = cvtpk(h1lo[0], h1lo[1]); h1f.u[1] = cvtpk(h1lo[2], h1lo[3]);
    h1f.u[2] = cvtpk(h1hi[0], h1hi[1]); h1f.u[3] = cvtpk(h1hi[2], h1hi[3]);

    // ---- GEMM2: Z2^T = W2^T @ H1^T ----
    f32x4 d2a = mfma16(w2af.v, h1f.v, zro);
    f32x4 d2b = mfma16(w2bf.v, h1f.v, zro);
    float h2lo[4], h2hi[4];
    unsigned m2lo[4], m2hi[4];
#pragma unroll
    for (int i = 0; i < 4; ++i) {
      float za = d2a[i] + b2l[i];
      float zb = d2b[i] + b2h[i];
      m2lo[i] = (za > 0.f) ? 0x3F80u : 0u;
      m2hi[i] = (zb > 0.f) ? 0x3F80u : 0u;
      h2lo[i] = fmaxf(za, 0.f);
      h2hi[i] = fmaxf(zb, 0.f);
    }
    Frag h2f;
    h2f.u[0] = cvtpk(h2lo[0], h2lo[1]); h2f.u[1] = cvtpk(h2lo[2], h2lo[3]);
    h2f.u[2] = cvtpk(h2hi[0], h2hi[1]); h2f.u[3] = cvtpk(h2hi[2], h2hi[3]);
    Frag m2f;
    m2f.u[0] = m2lo[0] | (m2lo[1] << 16); m2f.u[1] = m2lo[2] | (m2lo[3] << 16);
    m2f.u[2] = m2hi[0] | (m2hi[1] << 16); m2f.u[3] = m2hi[2] | (m2hi[3] << 16);

    // ---- head: P^T = W3^T @ H2^T, errc (g==0 lanes hold k=0..3) ----
    f32x4 pacc = mfma16(w3f.v, h2f.v, zro);
    if (g == 0) {
      float4 t4 = *reinterpret_cast<const float4*>(tgtc + (size_t)(s0 + c) * kK);
      float tv[4] = {t4.x, t4.y, t4.z, t4.w};
#pragma unroll
      for (int i = 0; i < 4; ++i) {
        float d = (pacc[i] + b3a[i]) - tv[i];
        errc = fmaf(d, d, errc);
      }
    }

    // ---- Jacobian: per k: C_k^T = U_k^T @ M2^T; T^T = m1.*C; J^T = W1x @ T^T
#pragma unroll
    for (int k = 0; k < 4; ++k) {
      f32x4 ca = mfma16(uka[k].v, m2f.v, zro);
      f32x4 cb = mfma16(ukb[k].v, m2f.v, zro);
      float ta[4], tb[4];
#pragma unroll
      for (int i = 0; i < 4; ++i) {
        ta[i] = ca[i] * m1a[i];
        tb[i] = cb[i] * m1b[i];
      }
      Frag tf;
      tf.u[0] = cvtpk(ta[0], ta[1]); tf.u[1] = cvtpk(ta[2], ta[3]);
      tf.u[2] = cvtpk(tb[0], tb[1]); tf.u[3] = cvtpk(tb[2], tb[3]);
#pragma unroll
      for (int jj = 0; jj < 3; ++jj) {
        f32x4 j4 = mfma16(w1vf[jj].v, tf.v, zro);
        if (jj < 2) {
          float4 t4 = (jj == 0) ? tg0[k] : tg1[k];
          float tv[4] = {t4.x, t4.y, t4.z, t4.w};
#pragma unroll
          for (int i = 0; i < 4; ++i) {
            float d = j4[i] - tv[i];
            errg = fmaf(d, d, errg);
          }
        } else if (g == 0) {
          float4 t4 = *reinterpret_cast<const float4*>(gpb + k * kXU + 32);
          float tv[4] = {t4.x, t4.y, t4.z, t4.w};
#pragma unroll
          for (int i = 0; i < 4; ++i) {
            float d = j4[i] - tv[i];
            errg = fmaf(d, d, errg);
          }
        }
      }
    }
  }

  // ---- wave reduction (deterministic), one partial pair per wave ----
#pragma unroll
  for (int off = 32; off > 0; off >>= 1) {
    errc += __shfl_down(errc, off);
    errg += __shfl_down(errg, off);
  }
  if (l == 0) { pc[wid] = errc; pg[wid] = errg; }
}

// ---------------------------------------------------------------------------
// finalize: reduce 512 kl + 4096 pc + 4096 pg partials, write loss
// ---------------------------------------------------------------------------
__global__ __launch_bounds__(256) void finalize_kernel(
    const float* __restrict__ ws, float* __restrict__ out)
{
  const int tid = threadIdx.x;
  float kl = ws[tid] + ws[tid + 256];
  float cs = 0.f, gs = 0.f;
#pragma unroll
  for (int i = 0; i < 16; ++i) {
    cs += ws[512 + tid + i * 256];
    gs += ws[512 + 4096 + tid + i * 256];
  }
  __shared__ float rk[256], rc[256], rg[256];
  rk[tid] = kl; rc[tid] = cs; rg[tid] = gs;
  __syncthreads();
  for (int off = 128; off > 0; off >>= 1) {
    if (tid < off) {
      rk[tid] += rk[tid + off];
      rc[tid] += rc[tid + off];
      rg[tid] += rg[tid + off];
    }
    __syncthreads();
  }
  if (tid == 0) {
    out[0] = rc[0] / (float)(kBT * kK)
           + rg[0] / ((float)kBT * (float)(kK * kXU))
           + rk[0] / (float)(kB * kCTX);
  }
}

// ---------------------------------------------------------------------------
extern "C" void kernel_launch(void* const* d_in, const int* in_sizes, int n_in,
                              void* d_out, int out_size, void* d_ws, size_t ws_size,
                              hipStream_t stream)
{
  const float* traj = (const float*)d_in[0];
  const float* tgtc = (const float*)d_in[1];
  const float* tgtg = (const float*)d_in[2];
  const float* mu   = (const float*)d_in[3];
  const float* sg   = (const float*)d_in[4];
  const float* nz   = (const float*)d_in[5];
  const float* W1   = (const float*)d_in[6];
  const float* b1   = (const float*)d_in[7];
  const float* W2   = (const float*)d_in[8];
  const float* b2   = (const float*)d_in[9];
  const float* W3   = (const float*)d_in[10];
  const float* b3   = (const float*)d_in[11];

  float* out = (float*)d_out;
  float* ws  = (float*)d_ws;
  float* kl_part = ws;            // [0, 512)
  float* pc      = ws + 512;      // [512, 4608)
  float* pg      = ws + 4608;     // [4608, 8704)

  ctx_kl_kernel<<<kNC, 256, 0, stream>>>(mu, sg, nz, out + 1, kl_part);
  main_mfma<<<kMainBlocks, 256, 0, stream>>>(traj, tgtc, tgtg, mu, sg, nz,
                                             W1, b1, W2, b2, W3, b3, pc, pg);
  finalize_kernel<<<1, 256, 0, stream>>>(ws, out);
}